// Round 1
// baseline (3084.463 us; speedup 1.0000x reference)
//
#include <hip/hip_runtime.h>
#include <math.h>

typedef float2 cplx;
#define PI_D 3.14159265358979323846

__device__ __forceinline__ int iabs_(int v){ return v < 0 ? -v : v; }

// ======================= table kernels =======================
__global__ void k_tables(double* lf, double* wq){
  if(threadIdx.x == 0){
    lf[0] = 0.0;
    double acc = 0.0;
    for(int i = 1; i <= 128; ++i){ acc += log((double)i); lf[i] = acc; }
  }
  int t = threadIdx.x;
  int b, j, off;
  if(t < 64){ b = 32; j = t; off = 0; }
  else if(t < 96){ b = 16; j = t - 64; off = 64; }
  else if(t < 112){ b = 8; j = t - 96; off = 96; }
  else if(t < 120){ b = 4; j = t - 112; off = 112; }
  else return;
  double beta = PI_D * (2*j+1) / (4.0*b);
  double s = 0.0;
  for(int p = 0; p < b; ++p) s += sin((2*p+1)*beta) / (2*p+1);
  wq[off+j] = 2.0*PI_D/((double)b*b) * sin(beta) * s;
}

__global__ void k_twiddle(cplx* E, int nfreq, int n, int center, double sgn){
  int idx = blockIdx.x*blockDim.x + threadIdx.x;
  if(idx >= nfreq*n) return;
  int p = idx / n, a = idx % n;
  double ang = sgn * 2.0*PI_D * (double)(p-center) * (double)a / (double)n;
  E[idx] = make_float2((float)cos(ang), (float)sin(ang));
}

// Wigner-d, n=0 column only: out[j][l][m] (W-wide, centered)
__global__ void k_wigner_col0(const double* __restrict__ lf, float* __restrict__ out,
                              int nb, int Lmax, int W, int mode, int bq){
  int idx = blockIdx.x*blockDim.x + threadIdx.x;
  int total = nb*Lmax*W;
  if(idx >= total) return;
  int m = idx % W;
  int l = (idx/W) % Lmax;
  int j = idx/(W*Lmax);
  int cw = (W-1)/2;
  int mh = m - cw;
  float r = 0.f;
  if(iabs_(mh) <= l){
    double beta = (mode==0) ? PI_D*(2*j+1)/(4.0*bq) : PI_D*(j+1)/16.0;
    double cb = cos(0.5*beta), sb = sin(0.5*beta);
    double lcb = log(cb), lsb = log(sb);
    int k0 = (mh < 0) ? -mh : 0;
    int k1 = (mh > 0) ? (l - mh) : l;
    double s = 0.0;
    for(int k = k0; k <= k1; ++k){
      double logc = 0.5*(lf[l+mh] + lf[l-mh] + 2.0*lf[l])
                    - lf[l-k] - lf[k] - lf[mh+k] - lf[l-mh-k];
      double term = exp(logc + (double)(2*l - mh - 2*k)*lcb + (double)(mh + 2*k)*lsb);
      s += ((mh + k) & 1) ? -term : term;
    }
    r = (float)s;
  }
  out[idx] = r;
}

// Full Wigner-d: out[j][l][p][q] (W x W, centered, zero-padded)
__global__ void k_wigner_full(const double* __restrict__ lf, float* __restrict__ out,
                              int nb, int L, int W, int mode, int bq){
  int idx = blockIdx.x*blockDim.x + threadIdx.x;
  int total = nb*L*W*W;
  if(idx >= total) return;
  int q = idx % W;
  int p = (idx/W) % W;
  int l = (idx/(W*W)) % L;
  int j = idx/(W*W*L);
  int cw = (W-1)/2;
  int mh = p - cw, nh = q - cw;
  float r = 0.f;
  if(iabs_(mh) <= l && iabs_(nh) <= l){
    double beta = (mode==0) ? PI_D*(2*j+1)/(4.0*bq) : PI_D*(j+1)/16.0;
    double cb = cos(0.5*beta), sb = sin(0.5*beta);
    double lcb = log(cb), lsb = log(sb);
    int k0 = (nh - mh > 0) ? (nh - mh) : 0;
    int a1 = l + nh, b1 = l - mh;
    int k1 = (a1 < b1) ? a1 : b1;
    double s = 0.0;
    for(int k = k0; k <= k1; ++k){
      double logc = 0.5*(lf[l+mh] + lf[l-mh] + lf[l+nh] + lf[l-nh])
                    - lf[l+nh-k] - lf[k] - lf[mh-nh+k] - lf[l-mh-k];
      double term = exp(logc + (double)(2*l + nh - mh - 2*k)*lcb + (double)(mh - nh + 2*k)*lsb);
      s += ((mh - nh + k) & 1) ? -term : term;
    }
    r = (float)s;
  }
  out[idx] = r;
}

// ======================= layer-0 (S2) kernels =======================
// xf[c,i,j,m] = (1/64) sum_a x[c,i,j,a] * e^{-2pi i a mh/64}, mh in [-15,15]
__global__ void k_fft0(const float* __restrict__ x, cplx* __restrict__ xf, const cplx* __restrict__ E0f){
  int idx = blockIdx.x*blockDim.x + threadIdx.x;
  if(idx >= 1536*31) return;
  int m = idx % 31;
  int r = idx / 31;
  const float* xr = x + (size_t)r*64;
  float sr = 0.f, si = 0.f;
  for(int a = 0; a < 64; ++a){
    cplx e = E0f[m*64 + a];
    float v = xr[a];
    sr += v*e.x; si += v*e.y;
  }
  xf[idx] = make_float2(sr*(1.f/64.f), si*(1.f/64.f));
}

__global__ void k_what0(const float* __restrict__ w0, const cplx* __restrict__ E0f, cplx* __restrict__ what0){
  int idx = blockIdx.x*blockDim.x + threadIdx.x;
  if(idx >= 96*2*31) return;
  int m = idx % 31;
  int bi = (idx/31) & 1;
  int oi = idx/62;
  const float* wr = w0 + (size_t)oi*128 + bi*64;
  float sr = 0.f, si = 0.f;
  for(int a = 0; a < 64; ++a){
    cplx e = E0f[m*64 + a];
    float v = wr[a];
    sr += v*e.x; si += v*e.y;
  }
  what0[idx] = make_float2(sr, si);
}

__global__ void k_X0(const cplx* __restrict__ xf, const float* __restrict__ d032,
                     const double* __restrict__ wq32, cplx* __restrict__ X0){
  int idx = blockIdx.x*blockDim.x + threadIdx.x;
  if(idx >= 24*16*31) return;
  int m = idx % 31;
  int l = (idx/31) % 16;
  int ci = idx/(31*16);
  float sx = 0.f, sy = 0.f;
  if(iabs_(m-15) <= l){
    for(int j = 0; j < 64; ++j){
      float d = d032[((size_t)j*16 + l)*31 + m] * (float)wq32[j];
      cplx v = xf[((size_t)ci*64 + j)*31 + m];
      sx += d*v.x; sy += d*v.y;
    }
  }
  X0[idx] = make_float2(sx, sy);
}

__global__ void k_Psi0(const cplx* __restrict__ what0, const float* __restrict__ dg32, cplx* __restrict__ Psi0){
  int idx = blockIdx.x*blockDim.x + threadIdx.x;
  if(idx >= 96*16*31) return;
  int m = idx % 31;
  int l = (idx/31) % 16;
  int oi = idx/(31*16);
  float sx = 0.f, sy = 0.f;
  if(iabs_(m-15) <= l){
    for(int bi = 0; bi < 2; ++bi){
      float d = dg32[((size_t)bi*16 + l)*31 + m];
      cplx v = what0[((size_t)oi*2 + bi)*31 + m];
      sx += d*v.x; sy += d*v.y;
    }
  }
  Psi0[idx] = make_float2(sx, sy);
}

// Z[c,o,l,p,q] = sum_i X0[c,i,l,p] * conj(Psi0[o,i,l,q])
__global__ void k_Z0(const cplx* __restrict__ X0, const cplx* __restrict__ Psi0, cplx* __restrict__ Z){
  int idx = blockIdx.x*blockDim.x + threadIdx.x;
  if(idx >= 8*32*16*961) return;
  int q = idx % 31;
  int p = (idx/31) % 31;
  int l = (idx/961) % 16;
  int o = (idx/(961*16)) % 32;
  int c = idx/(961*16*32);
  float sx = 0.f, sy = 0.f;
  if(iabs_(p-15) <= l && iabs_(q-15) <= l){
    for(int i = 0; i < 3; ++i){
      cplx a = X0[(((size_t)c*3 + i)*16 + l)*31 + p];
      cplx b = Psi0[(((size_t)o*3 + i)*16 + l)*31 + q];
      sx += a.x*b.x + a.y*b.y;
      sy += a.y*b.x - a.x*b.y;
    }
  }
  Z[idx] = make_float2(sx, sy);
}

// ======================= generic SO3 kernels =======================
// Fused so3_ifft: g-step (Wigner sum) + both E-transforms, per (c*O+o, j) block.
__global__ void k_ifft(const cplx* __restrict__ Zt, const float* __restrict__ Wst,
                       const cplx* __restrict__ E, float* __restrict__ out,
                       int b, int C, int O){
  int M = 2*b-1, n2 = 2*b, cw = b-1;
  extern __shared__ char smem[];
  cplx* gt = (cplx*)smem;          // M*M
  cplx* Tt = gt + M*M;             // n2*M
  int blk = blockIdx.x;
  int j = blk % n2;
  int co = blk / n2;
  const cplx* Zp = Zt + (size_t)co * b * M * M;
  for(int t = threadIdx.x; t < M*M; t += blockDim.x){
    int p = t / M, q = t % M;
    int lmin = iabs_(p-cw); int l2 = iabs_(q-cw); if(l2 > lmin) lmin = l2;
    float sx = 0.f, sy = 0.f;
    for(int l = lmin; l < b; ++l){
      float w = Wst[(((size_t)j*b + l)*M + p)*M + q] * (float)(2*l+1);
      cplx z = Zp[((size_t)l*M + p)*M + q];
      sx += w*z.x; sy += w*z.y;
    }
    gt[t] = make_float2(sx, sy);
  }
  __syncthreads();
  for(int t = threadIdx.x; t < n2*M; t += blockDim.x){
    int a = t / M, q = t % M;
    float sx = 0.f, sy = 0.f;
    for(int p = 0; p < M; ++p){
      cplx e = E[p*n2 + a];
      cplx g = gt[p*M + q];
      sx += g.x*e.x - g.y*e.y;
      sy += g.x*e.y + g.y*e.x;
    }
    Tt[t] = make_float2(sx, sy);
  }
  __syncthreads();
  float* op = out + (size_t)co*n2*n2*n2 + (size_t)j*n2*n2;
  for(int t = threadIdx.x; t < n2*n2; t += blockDim.x){
    int a = t / n2, g = t % n2;
    float s = 0.f;
    for(int q = 0; q < M; ++q){
      cplx e = E[q*n2 + g];
      cplx T = Tt[a*M + q];
      s += T.x*e.x - T.y*e.y;   // real part only
    }
    op[t] = s;
  }
}

// Fused 2D forward DFT (alpha,gamma) with freq truncation to Mt, per (ci, j) block.
__global__ void k_fft2(const float* __restrict__ f, cplx* __restrict__ hf,
                       const cplx* __restrict__ E, int b, int Mt, int CI){
  int M = 2*b-1, n2 = 2*b;
  int off = (M - Mt)/2;
  extern __shared__ char smem[];
  float* ft = (float*)smem;                                // n2*n2
  cplx* Ft = (cplx*)(smem + sizeof(float)*n2*n2);          // n2*Mt
  int blk = blockIdx.x;
  int j = blk % n2, ci = blk / n2;
  const float* fp = f + ((size_t)ci*n2 + j)*n2*n2;
  for(int t = threadIdx.x; t < n2*n2; t += blockDim.x) ft[t] = fp[t];
  __syncthreads();
  for(int t = threadIdx.x; t < n2*Mt; t += blockDim.x){
    int a = t / Mt, q = t % Mt;
    float sr = 0.f, si = 0.f;
    for(int g = 0; g < n2; ++g){
      cplx e = E[(q+off)*n2 + g];     // use conj(e)
      float v = ft[a*n2 + g];
      sr += v*e.x; si -= v*e.y;
    }
    Ft[t] = make_float2(sr, si);
  }
  __syncthreads();
  float inv = 1.0f / ((float)n2*(float)n2);
  cplx* hp = hf + ((size_t)ci*n2 + j)*Mt*Mt;
  for(int t = threadIdx.x; t < Mt*Mt; t += blockDim.x){
    int p = t / Mt, q = t % Mt;
    float sx = 0.f, sy = 0.f;
    for(int a = 0; a < n2; ++a){
      cplx e = E[(p+off)*n2 + a];     // conj
      cplx F = Ft[a*Mt + q];
      sx += F.x*e.x + F.y*e.y;
      sy += F.y*e.x - F.x*e.y;
    }
    hp[t] = make_float2(sx*inv, sy*inv);
  }
}

// X[ci,l,p,q] = sum_j wq[j]*W[j,l,p,q]*hf[ci,j,p,q]
__global__ void k_Xstep(const cplx* __restrict__ hf, const float* __restrict__ Wst,
                        const double* __restrict__ wqp, cplx* __restrict__ X,
                        int b, int Lout, int Mt, int CI){
  int M = 2*b-1, n2 = 2*b;
  int off = (M - Mt)/2, cw = (Mt-1)/2;
  int total = CI*Lout*Mt*Mt;
  int idx = blockIdx.x*blockDim.x + threadIdx.x;
  if(idx >= total) return;
  int q = idx % Mt;
  int p = (idx/Mt) % Mt;
  int l = (idx/(Mt*Mt)) % Lout;
  int ci = idx/(Mt*Mt*Lout);
  float sx = 0.f, sy = 0.f;
  if(iabs_(p-cw) <= l && iabs_(q-cw) <= l){
    for(int j = 0; j < n2; ++j){
      float w = Wst[(((size_t)j*b + l)*M + p + off)*M + q + off] * (float)wqp[j];
      cplx v = hf[(((size_t)ci*n2 + j)*Mt + p)*Mt + q];
      sx += w*v.x; sy += w*v.y;
    }
  }
  X[idx] = make_float2(sx, sy);
}

// what[oi,bi,p] = sum_a (w[..,2a]+w[..,2a+1]) * e^{-2pi i a ph/n2}  (gamma phase == 1)
__global__ void k_what(const float* __restrict__ w, cplx* __restrict__ what,
                       const cplx* __restrict__ E, int n2, int Mt, int off, int OI){
  int total = OI*2*Mt;
  int idx = blockIdx.x*blockDim.x + threadIdx.x;
  if(idx >= total) return;
  int p = idx % Mt;
  int bi = (idx/Mt) & 1;
  int oi = idx/(2*Mt);
  const float* wr = w + (size_t)oi*4*n2 + (size_t)bi*2*n2;
  float sr = 0.f, si = 0.f;
  for(int a = 0; a < n2; ++a){
    float v = wr[2*a] + wr[2*a+1];
    cplx e = E[(p+off)*n2 + a];     // conj
    sr += v*e.x; si -= v*e.y;
  }
  what[idx] = make_float2(sr, si);
}

// Z[c,o,l,p,q] = sum_{i,k} X[c,i,l,p,k] * conj(Psi[o,i,l,q,k]),
// Psi reconstructed on the fly: Psi = Dg0[l,q,k]*what[o,i,0,q] + Dg1[l,q,k]*what[o,i,1,q]
__global__ void k_zconv(const cplx* __restrict__ X, const cplx* __restrict__ what,
                        const float* __restrict__ Dg, cplx* __restrict__ Z,
                        int C, int O, int I, int Wt, int Wd, int Lx, int Ld){
  int l = blockIdx.z;
  int Lz = gridDim.z;
  int cw = (Wt-1)/2;
  int offd = (Wd-1)/2 - cw;
  int K21 = 2*l+1;
  int K = I*K21;
  int koff = cw - l;
  int tx = threadIdx.x, ty = threadIdx.y;
  int row = blockIdx.x*16 + ty;   // c*Wt + p
  int col = blockIdx.y*16 + tx;   // o*Wt + q
  int RM = C*Wt, CN = O*Wt;
  int c = row / Wt, p = row % Wt;
  int o = col / Wt, q = col % Wt;
  bool rv = (row < RM) && (iabs_(p-cw) <= l);
  bool cv = (col < CN) && (iabs_(q-cw) <= l);
  __shared__ int anyv;
  if(tx == 0 && ty == 0) anyv = 0;
  __syncthreads();
  if(rv && cv) anyv = 1;
  __syncthreads();
  size_t zidx = ((((size_t)c*O + o)*Lz + l)*Wt + p)*Wt + q;
  if(!anyv){
    if(row < RM && col < CN) Z[zidx] = make_float2(0.f, 0.f);
    return;
  }
  __shared__ cplx As[16][17];
  __shared__ cplx Bs[16][17];
  float accx = 0.f, accy = 0.f;
  for(int kk = 0; kk < K; kk += 16){
    {
      int kidx = kk + tx;
      cplx v = make_float2(0.f, 0.f);
      if(kidx < K && row < RM && iabs_(p-cw) <= l){
        int i = kidx / K21, kr = kidx % K21;
        int ks = kr + koff;
        v = X[((((size_t)c*I + i)*Lx + l)*Wt + p)*Wt + ks];
      }
      As[ty][tx] = v;
    }
    {
      int kidx = kk + tx;
      int c2 = blockIdx.y*16 + ty;
      cplx v = make_float2(0.f, 0.f);
      if(kidx < K && c2 < CN){
        int oo = c2 / Wt, qq = c2 % Wt;
        if(iabs_(qq-cw) <= l){
          int i = kidx / K21, kr = kidx % K21;
          int ks = kr + koff;
          int qf = qq + offd, kf = ks + offd;
          float dv0 = Dg[(((size_t)0*Ld + l)*Wd + qf)*Wd + kf];
          float dv1 = Dg[(((size_t)1*Ld + l)*Wd + qf)*Wd + kf];
          cplx wv0 = what[(((size_t)oo*I + i)*2 + 0)*Wt + qq];
          cplx wv1 = what[(((size_t)oo*I + i)*2 + 1)*Wt + qq];
          v = make_float2(dv0*wv0.x + dv1*wv1.x, -(dv0*wv0.y + dv1*wv1.y)); // conj(Psi)
        }
      }
      Bs[ty][tx] = v;
    }
    __syncthreads();
    int kmax = K - kk; if(kmax > 16) kmax = 16;
    for(int t = 0; t < kmax; ++t){
      cplx a = As[ty][t];
      cplx b = Bs[tx][t];
      accx += a.x*b.x - a.y*b.y;
      accy += a.x*b.y + a.y*b.x;
    }
    __syncthreads();
  }
  if(row < RM && col < CN)
    Z[zidx] = (rv && cv) ? make_float2(accx, accy) : make_float2(0.f, 0.f);
}

// Identity-grid conv: Z[c,o,l,p,q] = sum_i X[c,i,l,p,q] * w[o,i]
__global__ void k_zid(const cplx* __restrict__ X, const float* __restrict__ w,
                      cplx* __restrict__ Z, int C, int O, int I, int Lz, int Wt, int Wx, int Lx){
  int total = C*O*Lz*Wt*Wt;
  int idx = blockIdx.x*blockDim.x + threadIdx.x;
  if(idx >= total) return;
  int q = idx % Wt;
  int p = (idx/Wt) % Wt;
  int l = (idx/(Wt*Wt)) % Lz;
  int o = (idx/(Wt*Wt*Lz)) % O;
  int c = idx/(Wt*Wt*Lz*O);
  int cw = (Wt-1)/2, offx = (Wx-Wt)/2;
  float sx = 0.f, sy = 0.f;
  if(iabs_(p-cw) <= l && iabs_(q-cw) <= l){
    for(int i = 0; i < I; ++i){
      cplx v = X[((((size_t)c*I + i)*Lx + l)*Wx + p + offx)*Wx + q + offx];
      float wv = w[o*I + i];
      sx += wv*v.x; sy += wv*v.y;
    }
  }
  Z[idx] = make_float2(sx, sy);
}

// ======================= norm / misc =======================
__global__ void k_gn(const float* __restrict__ x, const float* __restrict__ gam,
                     const float* __restrict__ bet, float* __restrict__ y,
                     int Cch, int G, int S, int relu){
  int n = blockIdx.x / G, g = blockIdx.x % G;
  int cpg = Cch / G;
  size_t base = ((size_t)n*Cch + (size_t)g*cpg)*S;
  int cnt = cpg*S;
  double s = 0.0, sq = 0.0;
  for(int t = threadIdx.x; t < cnt; t += blockDim.x){
    float v = x[base + t]; s += v; sq += (double)v*v;
  }
  __shared__ double rs[256], rq[256];
  int tid = threadIdx.x;
  rs[tid] = s; rq[tid] = sq;
  __syncthreads();
  for(int o = 128; o > 0; o >>= 1){
    if(tid < o){ rs[tid] += rs[tid+o]; rq[tid] += rq[tid+o]; }
    __syncthreads();
  }
  __shared__ float mu_s, inv_s;
  if(tid == 0){
    double m = rs[0]/cnt;
    double var = rq[0]/cnt - m*m;
    mu_s = (float)m;
    inv_s = (float)(1.0/sqrt(var + 1e-5));
  }
  __syncthreads();
  float mu = mu_s, inv = inv_s;
  for(int t = threadIdx.x; t < cnt; t += blockDim.x){
    int c = g*cpg + t/S;
    float v = (x[base+t]-mu)*inv*gam[c] + bet[c];
    y[base+t] = relu ? fmaxf(v, 0.f) : v;
  }
}

__global__ void k_bn(const float* __restrict__ x, const float* __restrict__ gam,
                     const float* __restrict__ bet, float* __restrict__ y,
                     int N, int Cch, int S){
  int c = blockIdx.x;
  int cnt = N*S;
  double s = 0.0, sq = 0.0;
  for(int t = threadIdx.x; t < cnt; t += blockDim.x){
    int n = t / S, sp = t % S;
    float v = x[((size_t)n*Cch + c)*S + sp];
    s += v; sq += (double)v*v;
  }
  __shared__ double rs[256], rq[256];
  int tid = threadIdx.x;
  rs[tid] = s; rq[tid] = sq;
  __syncthreads();
  for(int o = 128; o > 0; o >>= 1){
    if(tid < o){ rs[tid] += rs[tid+o]; rq[tid] += rq[tid+o]; }
    __syncthreads();
  }
  __shared__ float mu_s, inv_s;
  if(tid == 0){
    double m = rs[0]/cnt;
    double var = rq[0]/cnt - m*m;
    mu_s = (float)m;
    inv_s = (float)(1.0/sqrt(var + 1e-5));
  }
  __syncthreads();
  float mu = mu_s, inv = inv_s;
  float ga = gam[c], be = bet[c];
  for(int t = threadIdx.x; t < cnt; t += blockDim.x){
    int n = t / S, sp = t % S;
    size_t id = ((size_t)n*Cch + c)*S + sp;
    y[id] = (x[id]-mu)*inv*ga + be;
  }
}

__global__ void k_addrelu(const float* __restrict__ a, const float* __restrict__ b,
                          float* __restrict__ y, int n){
  int i = blockIdx.x*blockDim.x + threadIdx.x;
  if(i < n) y[i] = fmaxf(a[i] + b[i], 0.f);
}

__global__ void k_integrate(const float* __restrict__ h, const double* __restrict__ wq4,
                            float* __restrict__ out){
  int nc = blockIdx.x;   // n*128 + c
  const float* hp = h + (size_t)nc*512;
  float s = 0.f;
  for(int t = threadIdx.x; t < 512; t += 64){
    int j = t >> 6;
    s += hp[t] * (float)wq4[j];
  }
  for(int o = 32; o > 0; o >>= 1) s += __shfl_down(s, o);
  if(threadIdx.x == 0) out[nc] = s * (1.f/64.f);
}

// ======================= launch =======================
extern "C" void kernel_launch(void* const* d_in, const int* in_sizes, int n_in,
                              void* d_out, int out_size, void* d_ws, size_t ws_size,
                              hipStream_t stream){
  const float* xin = (const float*)d_in[0];
  const float* w0p = (const float*)d_in[1];
  const float* g0p = (const float*)d_in[2];
  const float* b0p = (const float*)d_in[3];
  const float* w1ap = (const float*)d_in[4];
  const float* g1ap = (const float*)d_in[5];
  const float* b1ap = (const float*)d_in[6];
  const float* w1bp = (const float*)d_in[7];
  const float* g1bp = (const float*)d_in[8];
  const float* b1bp = (const float*)d_in[9];
  const float* w1sp = (const float*)d_in[10];
  const float* g1sp = (const float*)d_in[11];
  const float* b1sp = (const float*)d_in[12];
  const float* w2ap = (const float*)d_in[13];
  const float* g2ap = (const float*)d_in[14];
  const float* b2ap = (const float*)d_in[15];
  const float* w2bp = (const float*)d_in[16];
  const float* g2bp = (const float*)d_in[17];
  const float* b2bp = (const float*)d_in[18];
  const float* w2sp = (const float*)d_in[19];
  const float* g2sp = (const float*)d_in[20];
  const float* b2sp = (const float*)d_in[21];
  float* outp = (float*)d_out;

  char* ws = (char*)d_ws;
  size_t off = 0;
  auto alloc = [&](size_t bytes)->char*{
    char* p = ws + off;
    off = (off + bytes + 255) & ~(size_t)255;
    return p;
  };
  // tables (persistent)
  double* lf   = (double*)alloc(130*8);
  double* wq   = (double*)alloc(120*8);      // [0:64) b32, [64:96) b16, [96:112) b8, [112:120) b4
  cplx* E16    = (cplx*)alloc(31*32*8);
  cplx* E8     = (cplx*)alloc(15*16*8);
  cplx* E4     = (cplx*)alloc(7*8*8);
  cplx* E0f    = (cplx*)alloc(31*64*8);
  float* d032  = (float*)alloc((size_t)64*16*31*4);
  float* dg32  = (float*)alloc((size_t)2*16*31*4);
  float* W16   = (float*)alloc((size_t)32*16*961*4);
  float* Dg16  = (float*)alloc((size_t)2*16*961*4);
  float* W8    = (float*)alloc((size_t)16*8*225*4);
  float* Dg8   = (float*)alloc((size_t)2*8*225*4);
  float* W4    = (float*)alloc((size_t)8*4*49*4);
  // arenas (explicit reuse; liveness verified per stage)
  char* A_ZHF = alloc((size_t)63*1024*1024);   // Z / hf alternate here (never live together)
  char* A_X   = alloc((size_t)32*1024*1024);   // X1 then X2
  char* A_H1  = alloc((size_t)34*1024*1024);
  char* A_H2  = alloc((size_t)34*1024*1024);
  char* A_S   = alloc((size_t)8*1024*1024);    // small per-phase scratch

  // phase aliases
  cplx* xf0    = (cplx*)(A_S);
  cplx* X0     = (cplx*)(A_S + (512<<10));
  cplx* what0  = (cplx*)(A_S + (768<<10));
  cplx* Psi0   = (cplx*)(A_S + (1<<20));
  cplx* Zt0    = (cplx*)A_ZHF;
  float* h0    = (float*)A_H1;
  float* h0n   = (float*)A_H2;
  cplx* hf1    = (cplx*)A_ZHF;
  cplx* X1     = (cplx*)A_X;
  cplx* what1a = (cplx*)A_S;
  cplx* Z1a    = (cplx*)A_ZHF;
  float* left1 = (float*)A_H1;
  float* left1n= (float*)A_H2;
  cplx* hf1b   = (cplx*)A_ZHF;
  cplx* X1b    = (cplx*)A_S;
  cplx* what1b = (cplx*)(A_S + (4<<20));
  cplx* Z1b    = (cplx*)A_ZHF;
  float* left2 = (float*)A_H1;
  float* left2n= (float*)(A_H1 + (16<<20));
  cplx* Z1s    = (cplx*)A_ZHF;
  float* sc1   = (float*)A_H2;
  float* sc1n  = (float*)(A_H2 + (16<<20));
  float* h1    = (float*)A_H1;
  cplx* hf2    = (cplx*)A_ZHF;
  cplx* X2     = (cplx*)A_X;
  cplx* what2a = (cplx*)A_S;
  cplx* Z2a    = (cplx*)A_ZHF;
  float* left3 = (float*)A_H2;
  float* left3n= (float*)(A_H2 + (16<<20));
  cplx* hf2b   = (cplx*)A_ZHF;
  cplx* X2b    = (cplx*)A_S;
  cplx* what2b = (cplx*)(A_S + (1<<20));
  cplx* Z2b    = (cplx*)A_ZHF;
  float* left4 = (float*)A_H1;
  float* left4n= (float*)(A_H1 + (4<<20));
  cplx* Z2s    = (cplx*)A_ZHF;
  float* sc2   = (float*)A_H2;
  float* sc2n  = (float*)(A_H2 + (4<<20));
  float* h2    = (float*)(A_H1 + (8<<20));

  // ---- tables ----
  k_tables<<<1,256,0,stream>>>(lf, wq);
  k_twiddle<<<(31*32+255)/256,256,0,stream>>>(E16, 31, 32, 15,  1.0);
  k_twiddle<<<1,256,0,stream>>>(E8, 15, 16, 7,  1.0);
  k_twiddle<<<1,64,0,stream>>>(E4, 7, 8, 3,  1.0);
  k_twiddle<<<(31*64+255)/256,256,0,stream>>>(E0f, 31, 64, 15, -1.0);
  k_wigner_col0<<<(64*16*31+255)/256,256,0,stream>>>(lf, d032, 64, 16, 31, 0, 32);
  k_wigner_col0<<<(2*16*31+255)/256,256,0,stream>>>(lf, dg32, 2, 16, 31, 1, 0);
  k_wigner_full<<<(32*16*961+255)/256,256,0,stream>>>(lf, W16, 32, 16, 31, 0, 16);
  k_wigner_full<<<(2*16*961+255)/256,256,0,stream>>>(lf, Dg16, 2, 16, 31, 1, 0);
  k_wigner_full<<<(16*8*225+255)/256,256,0,stream>>>(lf, W8, 16, 8, 15, 0, 8);
  k_wigner_full<<<(2*8*225+255)/256,256,0,stream>>>(lf, Dg8, 2, 8, 15, 1, 0);
  k_wigner_full<<<(8*4*49+255)/256,256,0,stream>>>(lf, W4, 8, 4, 7, 0, 4);

  // ---- layer 0: s2_conv(x, w0, 32, 16) + GN + ReLU ----
  k_fft0<<<(1536*31+255)/256,256,0,stream>>>(xin, xf0, E0f);
  k_what0<<<(96*2*31+255)/256,256,0,stream>>>(w0p, E0f, what0);
  k_X0<<<(24*16*31+255)/256,256,0,stream>>>(xf0, d032, wq, X0);
  k_Psi0<<<(96*16*31+255)/256,256,0,stream>>>(what0, dg32, Psi0);
  k_Z0<<<(8*32*16*961+255)/256,256,0,stream>>>(X0, Psi0, Zt0);
  k_ifft<<<8*32*32,256,(961+992)*8,stream>>>(Zt0, W16, E16, h0, 16, 8, 32);
  k_gn<<<8*16,256,0,stream>>>(h0, g0p, b0p, h0n, 32, 16, 32768, 1);

  // ---- layer 1a: so3_conv(h, w1a, 16, 16) + GN ----
  k_fft2<<<256*32,256,4096+32*31*8,stream>>>(h0n, hf1, E16, 16, 31, 256);
  k_Xstep<<<(256*16*961+255)/256,256,0,stream>>>(hf1, W16, wq+64, X1, 16, 16, 31, 256);
  k_what<<<(1024*2*31+255)/256,256,0,stream>>>(w1ap, what1a, E16, 32, 31, 0, 1024);
  { dim3 g(16,62,16), blk(16,16);
    k_zconv<<<g,blk,0,stream>>>(X1, what1a, Dg16, Z1a, 8, 32, 32, 31, 31, 16, 16); }
  k_ifft<<<8*32*32,256,(961+992)*8,stream>>>(Z1a, W16, E16, left1, 16, 8, 32);
  k_gn<<<8*16,256,0,stream>>>(left1, g1ap, b1ap, left1n, 32, 16, 32768, 0);

  // ---- layer 1b: so3_conv(left, w1b, 16, 8) + GN + ReLU ----
  k_fft2<<<256*32,256,4096+32*15*8,stream>>>(left1n, hf1b, E16, 16, 15, 256);
  k_Xstep<<<(256*8*225+255)/256,256,0,stream>>>(hf1b, W16, wq+64, X1b, 16, 8, 15, 256);
  k_what<<<(2048*2*15+255)/256,256,0,stream>>>(w1bp, what1b, E16, 32, 15, 8, 2048);
  { dim3 g(8,60,8), blk(16,16);
    k_zconv<<<g,blk,0,stream>>>(X1b, what1b, Dg16, Z1b, 8, 64, 32, 15, 31, 8, 16); }
  k_ifft<<<8*64*16,256,(225+240)*8,stream>>>(Z1b, W8, E8, left2, 8, 8, 64);
  k_gn<<<8*16,256,0,stream>>>(left2, g1bp, b1bp, left2n, 64, 16, 4096, 1);

  // ---- layer 1s: so3_conv(h, w1s, 16, 8, ID) + BN ; residual add ----
  k_zid<<<(8*64*8*225+255)/256,256,0,stream>>>(X1, w1sp, Z1s, 8, 64, 32, 8, 15, 31, 16);
  k_ifft<<<8*64*16,256,(225+240)*8,stream>>>(Z1s, W8, E8, sc1, 8, 8, 64);
  k_bn<<<64,256,0,stream>>>(sc1, g1sp, b1sp, sc1n, 8, 64, 4096);
  k_addrelu<<<(2097152+255)/256,256,0,stream>>>(left2n, sc1n, h1, 2097152);

  // ---- layer 2a: so3_conv(h, w2a, 8, 8) + GN ----
  k_fft2<<<512*16,256,1024+16*15*8,stream>>>(h1, hf2, E8, 8, 15, 512);
  k_Xstep<<<(512*8*225+255)/256,256,0,stream>>>(hf2, W8, wq+96, X2, 8, 8, 15, 512);
  k_what<<<(4096*2*15+255)/256,256,0,stream>>>(w2ap, what2a, E8, 16, 15, 0, 4096);
  { dim3 g(8,60,8), blk(16,16);
    k_zconv<<<g,blk,0,stream>>>(X2, what2a, Dg8, Z2a, 8, 64, 64, 15, 15, 8, 8); }
  k_ifft<<<8*64*16,256,(225+240)*8,stream>>>(Z2a, W8, E8, left3, 8, 8, 64);
  k_gn<<<8*16,256,0,stream>>>(left3, g2ap, b2ap, left3n, 64, 16, 4096, 0);

  // ---- layer 2b: so3_conv(left, w2b, 8, 4) + GN + ReLU ----
  k_fft2<<<512*16,256,1024+16*7*8,stream>>>(left3n, hf2b, E8, 8, 7, 512);
  k_Xstep<<<(512*4*49+255)/256,256,0,stream>>>(hf2b, W8, wq+96, X2b, 8, 4, 7, 512);
  k_what<<<(8192*2*7+255)/256,256,0,stream>>>(w2bp, what2b, E8, 16, 7, 4, 8192);
  { dim3 g(4,56,4), blk(16,16);
    k_zconv<<<g,blk,0,stream>>>(X2b, what2b, Dg8, Z2b, 8, 128, 64, 7, 15, 4, 8); }
  k_ifft<<<8*128*8,64,(49+56)*8,stream>>>(Z2b, W4, E4, left4, 4, 8, 128);
  k_gn<<<8*32,256,0,stream>>>(left4, g2bp, b2bp, left4n, 128, 32, 512, 1);

  // ---- layer 2s: so3_conv(h, w2s, 8, 4, ID) + BN ; residual add ----
  k_zid<<<(8*128*4*49+255)/256,256,0,stream>>>(X2, w2sp, Z2s, 8, 128, 64, 4, 7, 15, 8);
  k_ifft<<<8*128*8,64,(49+56)*8,stream>>>(Z2s, W4, E4, sc2, 4, 8, 128);
  k_bn<<<128,256,0,stream>>>(sc2, g2sp, b2sp, sc2n, 8, 128, 512);
  k_addrelu<<<(524288+255)/256,256,0,stream>>>(left4n, sc2n, h2, 524288);

  // ---- integrate ----
  k_integrate<<<1024,64,0,stream>>>(h2, wq+112, outp);
}